// Round 6
// baseline (232.989 us; speedup 1.0000x reference)
//
#include <hip/hip_runtime.h>
#include <hip/hip_bf16.h>

// ---------------------------------------------------------------------------
// KEPCE_GCN, round 6: fix occupancy starvation of bucket kernels.
//  R5 post-mortem: 782-block kernels left 1 block (4 waves) per CU ->
//  gather-latency bound. Now: 1024-thread blocks (16 waves/CU), predicated
//  unroll-4. Fat node math split into k_node2 (256thr x 391 blocks).
// ---------------------------------------------------------------------------

#define NNODES 100000
#define NREG   17
#define KB     782          // buckets = ceil(100000/128)
#define FB     512          // fill blocks
#define LSTR   37           // LDS row stride
#define ABSTR  4352         // 34*128 floats per bucket in ABg

// wsm element offsets (f32)
#define O_W0    0
#define O_B0    8
#define O_W1    16
#define O_B1    144
#define O_W2    160
#define O_B2C   672
#define O_WN    704
#define O_BN    1728
#define O_WE1   1760
#define O_BE1   3872
#define O_WE2   3904
#define O_BE2   3968
#define WSM_N   3970
#define O_H0    3972
#define O_TS    3992
#define O_NT    4008
#define O_U     4016   // 17*32
#define O_WWR   4560   // 17*32
#define O_M     5104   // 66*2
#define O_BIAS2 5236
#define WSM_TOTAL 6144

__device__ __forceinline__ float bf2f(unsigned short u) {
  union { float f; unsigned int i; } v; v.i = ((unsigned int)u) << 16; return v.f;
}
__device__ __forceinline__ unsigned short f2bf(float f) {
  union { float f; unsigned int i; } v; v.f = f;
  unsigned int x = v.i;
  return (unsigned short)((x + 0x7FFFu + ((x >> 16) & 1u)) >> 16);
}
__device__ __forceinline__ float relu_(float x) { return x > 0.f ? x : 0.f; }

__global__ __launch_bounds__(256) void k_detect(const unsigned short* ew, int* mode) {
  __shared__ int cnt;
  if (threadIdx.x == 0) cnt = 0;
  __syncthreads();
  int ok = 0;
  for (int i = threadIdx.x; i < 512; i += blockDim.x) {
    unsigned short h = ew[i];
    int e = (h >> 7) & 0xFF;
    if (!(h & 0x8000) && e >= 0x70 && e <= 0x7E) ok++;
  }
  atomicAdd(&cnt, ok);
  __syncthreads();
  if (threadIdx.x == 0) *mode = (cnt >= 400) ? 1 : 0;  // 1 = bf16
}

__global__ __launch_bounds__(256) void k_convert_small(
    const void* p0, const void* p1, const void* p2, const void* p3,
    const void* p4, const void* p5, const void* p6, const void* p7,
    const void* p8, const void* p9, const void* p10, const void* p11,
    const int* mode, float* wsm) {
  int idx = blockIdx.x * blockDim.x + threadIdx.x;
  if (idx >= WSM_N) return;
  const void* ptrs[12] = {p0,p1,p2,p3,p4,p5,p6,p7,p8,p9,p10,p11};
  const int offs[13] = {O_W0,O_B0,O_W1,O_B1,O_W2,O_B2C,O_WN,O_BN,O_WE1,O_BE1,O_WE2,O_BE2,WSM_N};
  int seg = 0;
  while (idx >= offs[seg + 1]) seg++;
  int k = idx - offs[seg];
  wsm[idx] = (*mode) ? bf2f(((const unsigned short*)ptrs[seg])[k])
                     : ((const float*)ptrs[seg])[k];
}

__global__ __launch_bounds__(64) void k_prep(float* wsm) {
  __shared__ float h0[16], ts[16];
  __shared__ int snt;
  int t = threadIdx.x;
  if (t < 16) {
    float acc = 0.f;
    for (int j = 0; j < 8; j++)
      acc += (wsm[O_W0 + j] + wsm[O_B0 + j]) * wsm[O_W1 + j * 16 + t];
    h0[t] = acc;
    wsm[O_H0 + t] = acc;
  }
  __syncthreads();
  if (t == 0) {
    int n = 0;
    for (int j = 0; j < 16; j++) {
      float h = h0[j], b = wsm[O_B1 + j];
      if (h != 0.f) {
        float tj = -b / h;
        if (tj > 0.f) {
          int p = n++;
          while (p > 0 && ts[p - 1] > tj) { ts[p] = ts[p - 1]; p--; }
          ts[p] = tj;
        }
      }
    }
    snt = n;
    wsm[O_NT] = (float)n;
    for (int i = 0; i < n; i++) wsm[O_TS + i] = ts[i];
  }
  __syncthreads();
  int n = snt;
  for (int r = 0; r <= n; r++) {
    float srep;
    if (n == 0) srep = 1.f;
    else if (r == 0) srep = ts[0] * 0.5f;
    else if (r == n) srep = ts[n - 1] * 2.f + 1.f;
    else srep = 0.5f * (ts[r - 1] + ts[r]);
    if (t < 32) {
      float uu = 0.f, ww = 0.f;
      for (int j = 0; j < 16; j++) {
        float h = h0[j], b = wsm[O_B1 + j];
        if (srep * h + b > 0.f) {
          float w2 = wsm[O_W2 + j * 32 + t];
          uu += h * w2;
          ww += b * w2;
        }
      }
      wsm[O_U + r * 32 + t] = uu;
      wsm[O_WWR + r * 32 + t] = ww;
    }
  }
  for (int i = t; i < 66; i += blockDim.x) {
    float m0 = 0.f, m1 = 0.f;
    for (int k = 0; k < 32; k++) {
      float w1 = wsm[O_WE1 + i * 32 + k];
      m0 += w1 * wsm[O_WE2 + k * 2 + 0];
      m1 += w1 * wsm[O_WE2 + k * 2 + 1];
    }
    wsm[O_M + i * 2 + 0] = m0;
    wsm[O_M + i * 2 + 1] = m1;
  }
  if (t == 0) {
    float b20 = wsm[O_BE2 + 0], b21 = wsm[O_BE2 + 1];
    for (int k = 0; k < 32; k++) {
      b20 += wsm[O_BE1 + k] * wsm[O_WE2 + k * 2 + 0];
      b21 += wsm[O_BE1 + k] * wsm[O_WE2 + k * 2 + 1];
    }
    wsm[O_BIAS2 + 0] = b20;
    wsm[O_BIAS2 + 1] = b21;
  }
}

// --- radix partition by dst>>7 (atomic-free, 3 stages) ---------------------
__global__ __launch_bounds__(256) void k_hist(const int* __restrict__ dst,
                                              int* __restrict__ counts,
                                              int E, int chunk) {
  __shared__ int h[KB];
  for (int i = threadIdx.x; i < KB; i += blockDim.x) h[i] = 0;
  __syncthreads();
  int b = blockIdx.x;
  int start = b * chunk, end = min(E, start + chunk);
  for (int e = start + threadIdx.x; e < end; e += blockDim.x)
    atomicAdd(&h[dst[e] >> 7], 1);
  __syncthreads();
  for (int i = threadIdx.x; i < KB; i += blockDim.x)
    counts[i * FB + b] = h[i];
}

__global__ __launch_bounds__(FB) void k_scanA(int* __restrict__ counts,
                                              int* __restrict__ totals) {
  __shared__ int s[FB];
  int k = blockIdx.x, t = threadIdx.x;
  int v = counts[k * FB + t];
  s[t] = v;
  __syncthreads();
  for (int off = 1; off < FB; off <<= 1) {
    int add = (t >= off) ? s[t - off] : 0;
    __syncthreads();
    s[t] += add;
    __syncthreads();
  }
  counts[k * FB + t] = s[t] - v;          // exclusive within bucket
  if (t == FB - 1) totals[k] = s[t];
}

__global__ __launch_bounds__(1024) void k_scanB(const int* __restrict__ totals,
                                                int* __restrict__ bases) {
  __shared__ int s[1024];
  int t = threadIdx.x;
  int v = (t < KB) ? totals[t] : 0;
  s[t] = v;
  __syncthreads();
  for (int off = 1; off < 1024; off <<= 1) {
    int add = (t >= off) ? s[t - off] : 0;
    __syncthreads();
    s[t] += add;
    __syncthreads();
  }
  if (t < KB) bases[t] = s[t] - v;
  if (t == KB - 1) bases[KB] = s[t];
}

__global__ __launch_bounds__(256) void k_fill(const int* __restrict__ src,
                                              const int* __restrict__ dst,
                                              const int* __restrict__ counts,
                                              const int* __restrict__ bases,
                                              unsigned int* __restrict__ recs,
                                              int E, int chunk) {
  __shared__ int cur[KB];
  int b = blockIdx.x;
  for (int i = threadIdx.x; i < KB; i += blockDim.x)
    cur[i] = bases[i] + counts[i * FB + b];
  __syncthreads();
  int start = b * chunk, end = min(E, start + chunk);
  for (int e = start + threadIdx.x; e < end; e += blockDim.x) {
    int d = dst[e];
    int k = d >> 7;
    int pos = atomicAdd(&cur[k], 1);
    recs[pos] = ((unsigned int)src[e] << 7) | (unsigned int)(d & 127);
  }
}

// --- per-bucket edge passes: 1024 threads = 16 waves/CU --------------------
#define UDG 4
__global__ __launch_bounds__(1024) void k_degdinv(const unsigned int* __restrict__ recs,
                                                  const int* __restrict__ bases,
                                                  float* __restrict__ dinv, int N) {
  __shared__ int cnt[128];
  if (threadIdx.x < 128) cnt[threadIdx.x] = 0;
  __syncthreads();
  int k = blockIdx.x;
  int s0 = bases[k], n = bases[k + 1] - s0;
  const unsigned int* rp = recs + s0;
  int tid = threadIdx.x, BD = blockDim.x;
  for (int base = 0; base < n; base += BD * UDG) {
    unsigned int r[UDG]; int ok[UDG];
#pragma unroll
    for (int u = 0; u < UDG; u++) {
      int idx = base + u * BD + tid;
      ok[u] = idx < n;
      r[u] = ok[u] ? rp[idx] : 0u;
    }
#pragma unroll
    for (int u = 0; u < UDG; u++)
      if (ok[u]) atomicAdd(&cnt[r[u] & 127u], 1);
  }
  __syncthreads();
  if (threadIdx.x < 128) {
    int v = k * 128 + threadIdx.x;
    if (v < N) dinv[v] = rsqrtf((float)cnt[threadIdx.x] + 1.0f);
  }
}

#define USA 4
__global__ __launch_bounds__(1024) void k_sA(const float* __restrict__ wsm,
                                             const unsigned int* __restrict__ recs,
                                             const int* __restrict__ bases,
                                             const float* __restrict__ dinv,
                                             float4* __restrict__ rec4, int N) {
  __shared__ float acc[128];
  __shared__ float ts[16];
  __shared__ int nt;
  if (threadIdx.x < 128) acc[threadIdx.x] = 0.f;
  if (threadIdx.x == 0) nt = (int)wsm[O_NT];
  if (threadIdx.x < 16) ts[threadIdx.x] = wsm[O_TS + threadIdx.x];
  __syncthreads();
  int k = blockIdx.x;
  int s0 = bases[k], n = bases[k + 1] - s0;
  const unsigned int* rp = recs + s0;
  int tid = threadIdx.x, BD = blockDim.x;
  for (int base = 0; base < n; base += BD * USA) {
    unsigned int r[USA]; int ok[USA];
#pragma unroll
    for (int u = 0; u < USA; u++) {
      int idx = base + u * BD + tid;
      ok[u] = idx < n;
      r[u] = ok[u] ? rp[idx] : 0u;
    }
    float dv[USA];
#pragma unroll
    for (int u = 0; u < USA; u++) dv[u] = ok[u] ? dinv[r[u] >> 7] : 0.f;
#pragma unroll
    for (int u = 0; u < USA; u++)
      if (ok[u]) atomicAdd(&acc[r[u] & 127u], dv[u]);
  }
  __syncthreads();
  if (threadIdx.x < 128) {
    int v = k * 128 + threadIdx.x;
    if (v < N) {
      float dv = dinv[v];
      float s = dv * (acc[threadIdx.x] + dv);
      int rr = 0;
      for (int i = 0; i < nt; i++) rr += (ts[i] < s) ? 1 : 0;
      rec4[v] = make_float4(dv * s, dv, __int_as_float(rr), 0.f);
    }
  }
}

#define UAB 4
__global__ __launch_bounds__(1024) void k_ABacc(const unsigned int* __restrict__ recs,
                                                const int* __restrict__ bases,
                                                const float4* __restrict__ rec4,
                                                float* __restrict__ ABg, int N) {
  __shared__ float L[128 * LSTR];
  for (int i = threadIdx.x; i < 128 * LSTR; i += blockDim.x) L[i] = 0.f;
  __syncthreads();
  int k = blockIdx.x;
  int s0 = bases[k], n = bases[k + 1] - s0;
  const unsigned int* rp = recs + s0;
  int tid = threadIdx.x, BD = blockDim.x;
  for (int base = 0; base < n; base += BD * UAB) {
    unsigned int r[UAB]; int ok[UAB];
#pragma unroll
    for (int u = 0; u < UAB; u++) {
      int idx = base + u * BD + tid;
      ok[u] = idx < n;
      r[u] = ok[u] ? rp[idx] : 0u;
    }
    float4 q[UAB];
#pragma unroll
    for (int u = 0; u < UAB; u++) {
      q[u] = make_float4(0.f, 0.f, 0.f, 0.f);
      if (ok[u]) q[u] = rec4[r[u] >> 7];
    }
#pragma unroll
    for (int u = 0; u < UAB; u++) {
      if (ok[u]) {
        int rowb = (int)(r[u] & 127u) * LSTR;
        int rr = __float_as_int(q[u].z);
        atomicAdd(&L[rowb + rr], q[u].x);
        atomicAdd(&L[rowb + NREG + rr], q[u].y);
      }
    }
  }
  __syncthreads();
  float* out = ABg + (size_t)k * ABSTR;
  for (int i = tid; i < 34 * 128; i += BD) {
    int r = i >> 7, v = i & 127;
    out[i] = L[v * LSTR + r];
  }
}

// per node: AB planes -> x2 -> x3 -> (ps, pd)
__global__ __launch_bounds__(256) void k_node2(const float* __restrict__ wsm,
                                               const float* __restrict__ ABg,
                                               const float4* __restrict__ rec4,
                                               float4* __restrict__ pspd, int N) {
  __shared__ float sU[NREG * 32], sW[NREG * 32], sB2[32], sWn[1024], sBn[32], sM[132];
  for (int i = threadIdx.x; i < NREG * 32; i += blockDim.x) {
    sU[i] = wsm[O_U + i];
    sW[i] = wsm[O_WWR + i];
  }
  for (int i = threadIdx.x; i < 1024; i += blockDim.x) sWn[i] = wsm[O_WN + i];
  if (threadIdx.x < 32) {
    sB2[threadIdx.x] = wsm[O_B2C + threadIdx.x];
    sBn[threadIdx.x] = wsm[O_BN + threadIdx.x];
  }
  for (int i = threadIdx.x; i < 132; i += blockDim.x) sM[i] = wsm[O_M + i];
  __syncthreads();
  int v = blockIdx.x * blockDim.x + threadIdx.x;
  if (v >= N) return;
  float4 self = rec4[v];
  float dv = self.y;
  int sr = __float_as_int(self.z);
  const float* pb = ABg + (size_t)(v >> 7) * ABSTR + (v & 127);
  float A[NREG], B[NREG];
#pragma unroll
  for (int r = 0; r < NREG; r++) {
    A[r] = pb[r * 128];
    B[r] = pb[(NREG + r) * 128];
  }
  float acc[32];
#pragma unroll
  for (int j = 0; j < 32; j++) acc[j] = 0.f;
#pragma unroll
  for (int r = 0; r < NREG; r++) {
    float Ar = A[r] + ((r == sr) ? self.x : 0.f);
    float Br = B[r] + ((r == sr) ? self.y : 0.f);
    if (Ar != 0.f || Br != 0.f) {
#pragma unroll
      for (int j = 0; j < 32; j++)
        acc[j] += Ar * sU[r * 32 + j] + Br * sW[r * 32 + j];
    }
  }
#pragma unroll
  for (int j = 0; j < 32; j++) acc[j] = relu_(dv * acc[j] + sB2[j]);  // x2
  float x3[32];
#pragma unroll
  for (int j = 0; j < 32; j++) {
    float a = sBn[j];
#pragma unroll
    for (int q2 = 0; q2 < 32; q2++) a += acc[q2] * sWn[q2 * 32 + j];
    x3[j] = relu_(a);
  }
  float ps0 = 0.f, ps1 = 0.f, pd0 = 0.f, pd1 = 0.f;
#pragma unroll
  for (int j = 0; j < 32; j++) {
    float x = x3[j];
    ps0 += x * sM[(2 + j) * 2 + 0];
    ps1 += x * sM[(2 + j) * 2 + 1];
    pd0 += x * sM[(34 + j) * 2 + 0];
    pd1 += x * sM[(34 + j) * 2 + 1];
  }
  pspd[v] = make_float4(ps0, ps1, pd0, pd1);
}

#define UE 4
__global__ __launch_bounds__(256) void k_edge(const float* __restrict__ wsm,
                                              const int* __restrict__ src,
                                              const int* __restrict__ dst,
                                              const void* __restrict__ ewraw,
                                              const void* __restrict__ ceraw,
                                              const float4* __restrict__ pspd,
                                              void* __restrict__ out,
                                              const int* __restrict__ mode, int E) {
  int e0 = (blockIdx.x * blockDim.x + threadIdx.x) * UE;
  bool bf = (*mode) != 0;
  float b0 = wsm[O_BIAS2 + 0], b1 = wsm[O_BIAS2 + 1];
  float M00 = wsm[O_M + 0], M01 = wsm[O_M + 1];
  float M10 = wsm[O_M + 2], M11 = wsm[O_M + 3];
  if (e0 + UE <= E) {
    int s[UE], d[UE];
#pragma unroll
    for (int u = 0; u < UE; u++) { s[u] = src[e0 + u]; d[u] = dst[e0 + u]; }
    float4 s4[UE], d4[UE];
#pragma unroll
    for (int u = 0; u < UE; u++) s4[u] = pspd[s[u]];
#pragma unroll
    for (int u = 0; u < UE; u++) d4[u] = pspd[d[u]];
#pragma unroll
    for (int u = 0; u < UE; u++) {
      int e = e0 + u;
      float ew = bf ? bf2f(((const unsigned short*)ewraw)[e]) : ((const float*)ewraw)[e];
      float ce = bf ? bf2f(((const unsigned short*)ceraw)[e]) : ((const float*)ceraw)[e];
      float o0 = b0 + ew * M00 + ce * M10 + s4[u].x + d4[u].z;
      float o1 = b1 + ew * M01 + ce * M11 + s4[u].y + d4[u].w;
      if (bf) {
        unsigned int pk = ((unsigned int)f2bf(o1) << 16) | (unsigned int)f2bf(o0);
        ((unsigned int*)out)[e] = pk;
      } else {
        float2 r; r.x = o0; r.y = o1;
        ((float2*)out)[e] = r;
      }
    }
  } else {
    for (int e = e0; e < E; e++) {
      float ew = bf ? bf2f(((const unsigned short*)ewraw)[e]) : ((const float*)ewraw)[e];
      float ce = bf ? bf2f(((const unsigned short*)ceraw)[e]) : ((const float*)ceraw)[e];
      float4 s4 = pspd[src[e]];
      float4 d4 = pspd[dst[e]];
      float o0 = b0 + ew * M00 + ce * M10 + s4.x + d4.z;
      float o1 = b1 + ew * M01 + ce * M11 + s4.y + d4.w;
      if (bf) {
        unsigned int pk = ((unsigned int)f2bf(o1) << 16) | (unsigned int)f2bf(o0);
        ((unsigned int*)out)[e] = pk;
      } else {
        float2 r; r.x = o0; r.y = o1;
        ((float2*)out)[e] = r;
      }
    }
  }
}

extern "C" void kernel_launch(void* const* d_in, const int* in_sizes, int n_in,
                              void* d_out, int out_size, void* d_ws, size_t ws_size,
                              hipStream_t stream) {
  const int* eidx = (const int*)d_in[0];
  const int E = in_sizes[0] / 2;
  const int N = NNODES;
  const int* src = eidx;
  const int* dst = eidx + E;
  const int chunk = (E + FB - 1) / FB;

  char* ws = (char*)d_ws;
  size_t off = 0;
  size_t off_mode = off; off += 256;
  size_t off_wsm  = off; off += (size_t)WSM_TOTAL * 4;
  off = (off + 255) & ~(size_t)255;
  size_t off_cnts = off; off += (size_t)KB * FB * 4;
  size_t off_tot  = off; off += (size_t)KB * 4;
  off = (off + 255) & ~(size_t)255;
  size_t off_base = off; off += (size_t)(KB + 1) * 4;
  off = (off + 255) & ~(size_t)255;
  size_t off_recs = off; off += (size_t)E * 4;
  size_t off_dinv = off; off += (size_t)N * 4;
  off = (off + 255) & ~(size_t)255;
  size_t off_rec4 = off; off += (size_t)N * 16;
  size_t off_pspd = off; off += (size_t)N * 16;
  off = (off + 255) & ~(size_t)255;
  size_t off_ABg  = off; off += (size_t)KB * ABSTR * 4;
  if (ws_size < off) return;

  int*          mode   = (int*)(ws + off_mode);
  float*        wsm    = (float*)(ws + off_wsm);
  int*          counts = (int*)(ws + off_cnts);
  int*          totals = (int*)(ws + off_tot);
  int*          bases  = (int*)(ws + off_base);
  unsigned int* recs   = (unsigned int*)(ws + off_recs);
  float*        dinv   = (float*)(ws + off_dinv);
  float4*       rec4   = (float4*)(ws + off_rec4);
  float4*       pspd   = (float4*)(ws + off_pspd);
  float*        ABg    = (float*)(ws + off_ABg);

  k_detect<<<1, 256, 0, stream>>>((const unsigned short*)d_in[1], mode);
  k_convert_small<<<(WSM_N + 255) / 256, 256, 0, stream>>>(
      d_in[4], d_in[5], d_in[6], d_in[7], d_in[8], d_in[9], d_in[10], d_in[11],
      d_in[12], d_in[13], d_in[14], d_in[15], mode, wsm);
  k_prep<<<1, 64, 0, stream>>>(wsm);
  k_hist<<<FB, 256, 0, stream>>>(dst, counts, E, chunk);
  k_scanA<<<KB, FB, 0, stream>>>(counts, totals);
  k_scanB<<<1, 1024, 0, stream>>>(totals, bases);
  k_fill<<<FB, 256, 0, stream>>>(src, dst, counts, bases, recs, E, chunk);
  k_degdinv<<<KB, 1024, 0, stream>>>(recs, bases, dinv, N);
  k_sA<<<KB, 1024, 0, stream>>>(wsm, recs, bases, dinv, rec4, N);
  k_ABacc<<<KB, 1024, 0, stream>>>(recs, bases, rec4, ABg, N);
  k_node2<<<(N + 255) / 256, 256, 0, stream>>>(wsm, ABg, rec4, pspd, N);
  {
    long long tot = ((long long)E + UE - 1) / UE;
    int blocks = (int)((tot + 255) / 256);
    k_edge<<<blocks, 256, 0, stream>>>(wsm, src, dst, d_in[1], d_in[2],
                                       pspd, d_out, mode, E);
  }
}

// Round 7
// 216.770 us; speedup vs baseline: 1.0748x; 1.0748x over previous
//
#include <hip/hip_runtime.h>
#include <hip/hip_bf16.h>

// ---------------------------------------------------------------------------
// KEPCE_GCN, round 7: kill k_fill's 6x write amplification.
//  k_fill (scattered 4B stores, 79MB HBM write) -> k_fillsort: per-block
//  in-LDS counting sort of a 12.5K-edge chunk, flushed as per-bucket
//  contiguous ~64B runs (full sectors, ~1x amplification).
//  Partition: dst>>7 -> 782 buckets of 128 nodes. Consumers unchanged (R6).
// ---------------------------------------------------------------------------

#define NNODES 100000
#define NREG   17
#define KB     782          // buckets = ceil(100000/128)
#define FBC    256          // fill/hist chunk blocks
#define STCAP  12544        // LDS staging capacity (>= chunk = ceil(E/FBC))
#define LSTR   37           // LDS row stride for AB planes
#define ABSTR  4352         // 34*128 floats per bucket in ABg

// wsm element offsets (f32)
#define O_W0    0
#define O_B0    8
#define O_W1    16
#define O_B1    144
#define O_W2    160
#define O_B2C   672
#define O_WN    704
#define O_BN    1728
#define O_WE1   1760
#define O_BE1   3872
#define O_WE2   3904
#define O_BE2   3968
#define WSM_N   3970
#define O_H0    3972
#define O_TS    3992
#define O_NT    4008
#define O_U     4016   // 17*32
#define O_WWR   4560   // 17*32
#define O_M     5104   // 66*2
#define O_BIAS2 5236
#define WSM_TOTAL 6144

__device__ __forceinline__ float bf2f(unsigned short u) {
  union { float f; unsigned int i; } v; v.i = ((unsigned int)u) << 16; return v.f;
}
__device__ __forceinline__ unsigned short f2bf(float f) {
  union { float f; unsigned int i; } v; v.f = f;
  unsigned int x = v.i;
  return (unsigned short)((x + 0x7FFFu + ((x >> 16) & 1u)) >> 16);
}
__device__ __forceinline__ float relu_(float x) { return x > 0.f ? x : 0.f; }

__global__ __launch_bounds__(256) void k_detect(const unsigned short* ew, int* mode) {
  __shared__ int cnt;
  if (threadIdx.x == 0) cnt = 0;
  __syncthreads();
  int ok = 0;
  for (int i = threadIdx.x; i < 512; i += blockDim.x) {
    unsigned short h = ew[i];
    int e = (h >> 7) & 0xFF;
    if (!(h & 0x8000) && e >= 0x70 && e <= 0x7E) ok++;
  }
  atomicAdd(&cnt, ok);
  __syncthreads();
  if (threadIdx.x == 0) *mode = (cnt >= 400) ? 1 : 0;  // 1 = bf16
}

__global__ __launch_bounds__(256) void k_convert_small(
    const void* p0, const void* p1, const void* p2, const void* p3,
    const void* p4, const void* p5, const void* p6, const void* p7,
    const void* p8, const void* p9, const void* p10, const void* p11,
    const int* mode, float* wsm) {
  int idx = blockIdx.x * blockDim.x + threadIdx.x;
  if (idx >= WSM_N) return;
  const void* ptrs[12] = {p0,p1,p2,p3,p4,p5,p6,p7,p8,p9,p10,p11};
  const int offs[13] = {O_W0,O_B0,O_W1,O_B1,O_W2,O_B2C,O_WN,O_BN,O_WE1,O_BE1,O_WE2,O_BE2,WSM_N};
  int seg = 0;
  while (idx >= offs[seg + 1]) seg++;
  int k = idx - offs[seg];
  wsm[idx] = (*mode) ? bf2f(((const unsigned short*)ptrs[seg])[k])
                     : ((const float*)ptrs[seg])[k];
}

__global__ __launch_bounds__(64) void k_prep(float* wsm) {
  __shared__ float h0[16], ts[16];
  __shared__ int snt;
  int t = threadIdx.x;
  if (t < 16) {
    float acc = 0.f;
    for (int j = 0; j < 8; j++)
      acc += (wsm[O_W0 + j] + wsm[O_B0 + j]) * wsm[O_W1 + j * 16 + t];
    h0[t] = acc;
    wsm[O_H0 + t] = acc;
  }
  __syncthreads();
  if (t == 0) {
    int n = 0;
    for (int j = 0; j < 16; j++) {
      float h = h0[j], b = wsm[O_B1 + j];
      if (h != 0.f) {
        float tj = -b / h;
        if (tj > 0.f) {
          int p = n++;
          while (p > 0 && ts[p - 1] > tj) { ts[p] = ts[p - 1]; p--; }
          ts[p] = tj;
        }
      }
    }
    snt = n;
    wsm[O_NT] = (float)n;
    for (int i = 0; i < n; i++) wsm[O_TS + i] = ts[i];
  }
  __syncthreads();
  int n = snt;
  for (int r = 0; r <= n; r++) {
    float srep;
    if (n == 0) srep = 1.f;
    else if (r == 0) srep = ts[0] * 0.5f;
    else if (r == n) srep = ts[n - 1] * 2.f + 1.f;
    else srep = 0.5f * (ts[r - 1] + ts[r]);
    if (t < 32) {
      float uu = 0.f, ww = 0.f;
      for (int j = 0; j < 16; j++) {
        float h = h0[j], b = wsm[O_B1 + j];
        if (srep * h + b > 0.f) {
          float w2 = wsm[O_W2 + j * 32 + t];
          uu += h * w2;
          ww += b * w2;
        }
      }
      wsm[O_U + r * 32 + t] = uu;
      wsm[O_WWR + r * 32 + t] = ww;
    }
  }
  for (int i = t; i < 66; i += blockDim.x) {
    float m0 = 0.f, m1 = 0.f;
    for (int k = 0; k < 32; k++) {
      float w1 = wsm[O_WE1 + i * 32 + k];
      m0 += w1 * wsm[O_WE2 + k * 2 + 0];
      m1 += w1 * wsm[O_WE2 + k * 2 + 1];
    }
    wsm[O_M + i * 2 + 0] = m0;
    wsm[O_M + i * 2 + 1] = m1;
  }
  if (t == 0) {
    float b20 = wsm[O_BE2 + 0], b21 = wsm[O_BE2 + 1];
    for (int k = 0; k < 32; k++) {
      b20 += wsm[O_BE1 + k] * wsm[O_WE2 + k * 2 + 0];
      b21 += wsm[O_BE1 + k] * wsm[O_WE2 + k * 2 + 1];
    }
    wsm[O_BIAS2 + 0] = b20;
    wsm[O_BIAS2 + 1] = b21;
  }
}

// --- radix partition by dst>>7 (atomic-free) -------------------------------
__global__ __launch_bounds__(1024) void k_hist(const int* __restrict__ dst,
                                               int* __restrict__ counts,
                                               int E, int chunk) {
  __shared__ int h[KB];
  for (int i = threadIdx.x; i < KB; i += blockDim.x) h[i] = 0;
  __syncthreads();
  int b = blockIdx.x;
  int start = b * chunk, end = min(E, start + chunk);
  int tid = threadIdx.x, BD = blockDim.x;
  for (int base = start; base < end; base += BD * 4) {
#pragma unroll
    for (int u = 0; u < 4; u++) {
      int idx = base + u * BD + tid;
      if (idx < end) atomicAdd(&h[dst[idx] >> 7], 1);
    }
  }
  __syncthreads();
  for (int i = threadIdx.x; i < KB; i += blockDim.x)
    counts[i * FBC + b] = h[i];
}

__global__ __launch_bounds__(FBC) void k_scanA(int* __restrict__ counts,
                                               int* __restrict__ totals) {
  __shared__ int s[FBC];
  int k = blockIdx.x, t = threadIdx.x;
  int v = counts[k * FBC + t];
  s[t] = v;
  __syncthreads();
  for (int off = 1; off < FBC; off <<= 1) {
    int add = (t >= off) ? s[t - off] : 0;
    __syncthreads();
    s[t] += add;
    __syncthreads();
  }
  counts[k * FBC + t] = s[t] - v;          // exclusive within bucket
  if (t == FBC - 1) totals[k] = s[t];
}

__global__ __launch_bounds__(1024) void k_scanB(const int* __restrict__ totals,
                                                int* __restrict__ bases) {
  __shared__ int s[1024];
  int t = threadIdx.x;
  int v = (t < KB) ? totals[t] : 0;
  s[t] = v;
  __syncthreads();
  for (int off = 1; off < 1024; off <<= 1) {
    int add = (t >= off) ? s[t - off] : 0;
    __syncthreads();
    s[t] += add;
    __syncthreads();
  }
  if (t < KB) bases[t] = s[t] - v;
  if (t == KB - 1) bases[KB] = s[t];
}

// in-LDS counting sort per chunk; flush = per-bucket contiguous runs
__global__ __launch_bounds__(1024) void k_fillsort(const int* __restrict__ src,
                                                   const int* __restrict__ dst,
                                                   const int* __restrict__ counts,
                                                   const int* __restrict__ bases,
                                                   unsigned int* __restrict__ recs,
                                                   int E, int chunk) {
  __shared__ unsigned int staged[STCAP];
  __shared__ int cnt[KB], r0o[KB + 1], r0c[KB], tgt[KB];
  int b = blockIdx.x;
  int tid = threadIdx.x, BD = blockDim.x;
  for (int i = tid; i < KB; i += BD)
    tgt[i] = bases[i] + counts[i * FBC + b];
  int start = b * chunk, end = min(E, start + chunk);
  for (int rs = start; rs < end; rs += STCAP) {
    int rn = min(STCAP, end - rs);
    // zero hist
    for (int i = tid; i < KB; i += BD) cnt[i] = 0;
    __syncthreads();
    // pass 1: histogram dst
    for (int base = 0; base < rn; base += BD * 4) {
#pragma unroll
      for (int u = 0; u < 4; u++) {
        int idx = base + u * BD + tid;
        if (idx < rn) atomicAdd(&cnt[dst[rs + idx] >> 7], 1);
      }
    }
    __syncthreads();
    // exclusive scan of cnt -> r0o (starts), r0c (cursors)
    if (tid < KB) r0o[tid] = cnt[tid];
    __syncthreads();
    for (int off = 1; off < KB; off <<= 1) {
      int add = 0;
      if (tid < KB && tid >= off) add = r0o[tid - off];
      __syncthreads();
      if (tid < KB) r0o[tid] += add;
      __syncthreads();
    }
    if (tid < KB) r0c[tid] = r0o[tid] - cnt[tid];   // exclusive
    __syncthreads();
    if (tid < KB) r0o[tid] = r0c[tid];
    if (tid == 0) r0o[KB] = rn;
    __syncthreads();
    // pass 2: scatter records into sorted LDS positions
    for (int base = 0; base < rn; base += BD * 4) {
#pragma unroll
      for (int u = 0; u < 4; u++) {
        int idx = base + u * BD + tid;
        if (idx < rn) {
          int d = dst[rs + idx];
          int s = src[rs + idx];
          int pos = atomicAdd(&r0c[d >> 7], 1);
          staged[pos] = ((unsigned int)s << 7) | (unsigned int)(d & 127);
        }
      }
    }
    __syncthreads();
    // flush: coalesced-in-runs global writes
    for (int t = tid; t < rn; t += BD) {
      unsigned int rec = staged[t];
      int lo = 0, hi = KB;                 // r0o[lo] <= t < r0o[hi]
      while (hi - lo > 1) {
        int mid = (lo + hi) >> 1;
        if (r0o[mid] <= t) lo = mid; else hi = mid;
      }
      recs[tgt[lo] + (t - r0o[lo])] = rec;
    }
    __syncthreads();
    if (tid < KB) tgt[tid] += cnt[tid];
    __syncthreads();
  }
}

// --- per-bucket edge passes: 1024 threads ----------------------------------
#define UDG 4
__global__ __launch_bounds__(1024) void k_degdinv(const unsigned int* __restrict__ recs,
                                                  const int* __restrict__ bases,
                                                  float* __restrict__ dinv, int N) {
  __shared__ int cnt[128];
  if (threadIdx.x < 128) cnt[threadIdx.x] = 0;
  __syncthreads();
  int k = blockIdx.x;
  int s0 = bases[k], n = bases[k + 1] - s0;
  const unsigned int* rp = recs + s0;
  int tid = threadIdx.x, BD = blockDim.x;
  for (int base = 0; base < n; base += BD * UDG) {
    unsigned int r[UDG]; int ok[UDG];
#pragma unroll
    for (int u = 0; u < UDG; u++) {
      int idx = base + u * BD + tid;
      ok[u] = idx < n;
      r[u] = ok[u] ? rp[idx] : 0u;
    }
#pragma unroll
    for (int u = 0; u < UDG; u++)
      if (ok[u]) atomicAdd(&cnt[r[u] & 127u], 1);
  }
  __syncthreads();
  if (threadIdx.x < 128) {
    int v = k * 128 + threadIdx.x;
    if (v < N) dinv[v] = rsqrtf((float)cnt[threadIdx.x] + 1.0f);
  }
}

#define USA 4
__global__ __launch_bounds__(1024) void k_sA(const float* __restrict__ wsm,
                                             const unsigned int* __restrict__ recs,
                                             const int* __restrict__ bases,
                                             const float* __restrict__ dinv,
                                             float4* __restrict__ rec4, int N) {
  __shared__ float acc[128];
  __shared__ float ts[16];
  __shared__ int nt;
  if (threadIdx.x < 128) acc[threadIdx.x] = 0.f;
  if (threadIdx.x == 0) nt = (int)wsm[O_NT];
  if (threadIdx.x < 16) ts[threadIdx.x] = wsm[O_TS + threadIdx.x];
  __syncthreads();
  int k = blockIdx.x;
  int s0 = bases[k], n = bases[k + 1] - s0;
  const unsigned int* rp = recs + s0;
  int tid = threadIdx.x, BD = blockDim.x;
  for (int base = 0; base < n; base += BD * USA) {
    unsigned int r[USA]; int ok[USA];
#pragma unroll
    for (int u = 0; u < USA; u++) {
      int idx = base + u * BD + tid;
      ok[u] = idx < n;
      r[u] = ok[u] ? rp[idx] : 0u;
    }
    float dv[USA];
#pragma unroll
    for (int u = 0; u < USA; u++) dv[u] = ok[u] ? dinv[r[u] >> 7] : 0.f;
#pragma unroll
    for (int u = 0; u < USA; u++)
      if (ok[u]) atomicAdd(&acc[r[u] & 127u], dv[u]);
  }
  __syncthreads();
  if (threadIdx.x < 128) {
    int v = k * 128 + threadIdx.x;
    if (v < N) {
      float dv = dinv[v];
      float s = dv * (acc[threadIdx.x] + dv);
      int rr = 0;
      for (int i = 0; i < nt; i++) rr += (ts[i] < s) ? 1 : 0;
      rec4[v] = make_float4(dv * s, dv, __int_as_float(rr), 0.f);
    }
  }
}

#define UAB 4
__global__ __launch_bounds__(1024) void k_ABacc(const unsigned int* __restrict__ recs,
                                                const int* __restrict__ bases,
                                                const float4* __restrict__ rec4,
                                                float* __restrict__ ABg, int N) {
  __shared__ float L[128 * LSTR];
  for (int i = threadIdx.x; i < 128 * LSTR; i += blockDim.x) L[i] = 0.f;
  __syncthreads();
  int k = blockIdx.x;
  int s0 = bases[k], n = bases[k + 1] - s0;
  const unsigned int* rp = recs + s0;
  int tid = threadIdx.x, BD = blockDim.x;
  for (int base = 0; base < n; base += BD * UAB) {
    unsigned int r[UAB]; int ok[UAB];
#pragma unroll
    for (int u = 0; u < UAB; u++) {
      int idx = base + u * BD + tid;
      ok[u] = idx < n;
      r[u] = ok[u] ? rp[idx] : 0u;
    }
    float4 q[UAB];
#pragma unroll
    for (int u = 0; u < UAB; u++) {
      q[u] = make_float4(0.f, 0.f, 0.f, 0.f);
      if (ok[u]) q[u] = rec4[r[u] >> 7];
    }
#pragma unroll
    for (int u = 0; u < UAB; u++) {
      if (ok[u]) {
        int rowb = (int)(r[u] & 127u) * LSTR;
        int rr = __float_as_int(q[u].z);
        atomicAdd(&L[rowb + rr], q[u].x);
        atomicAdd(&L[rowb + NREG + rr], q[u].y);
      }
    }
  }
  __syncthreads();
  float* out = ABg + (size_t)k * ABSTR;
  for (int i = tid; i < 34 * 128; i += BD) {
    int r = i >> 7, v = i & 127;
    out[i] = L[v * LSTR + r];
  }
}

// per node: AB planes -> x2 -> x3 -> (ps, pd)
__global__ __launch_bounds__(256) void k_node2(const float* __restrict__ wsm,
                                               const float* __restrict__ ABg,
                                               const float4* __restrict__ rec4,
                                               float4* __restrict__ pspd, int N) {
  __shared__ float sU[NREG * 32], sW[NREG * 32], sB2[32], sWn[1024], sBn[32], sM[132];
  for (int i = threadIdx.x; i < NREG * 32; i += blockDim.x) {
    sU[i] = wsm[O_U + i];
    sW[i] = wsm[O_WWR + i];
  }
  for (int i = threadIdx.x; i < 1024; i += blockDim.x) sWn[i] = wsm[O_WN + i];
  if (threadIdx.x < 32) {
    sB2[threadIdx.x] = wsm[O_B2C + threadIdx.x];
    sBn[threadIdx.x] = wsm[O_BN + threadIdx.x];
  }
  for (int i = threadIdx.x; i < 132; i += blockDim.x) sM[i] = wsm[O_M + i];
  __syncthreads();
  int v = blockIdx.x * blockDim.x + threadIdx.x;
  if (v >= N) return;
  float4 self = rec4[v];
  float dv = self.y;
  int sr = __float_as_int(self.z);
  const float* pb = ABg + (size_t)(v >> 7) * ABSTR + (v & 127);
  float A[NREG], B[NREG];
#pragma unroll
  for (int r = 0; r < NREG; r++) {
    A[r] = pb[r * 128];
    B[r] = pb[(NREG + r) * 128];
  }
  float acc[32];
#pragma unroll
  for (int j = 0; j < 32; j++) acc[j] = 0.f;
#pragma unroll
  for (int r = 0; r < NREG; r++) {
    float Ar = A[r] + ((r == sr) ? self.x : 0.f);
    float Br = B[r] + ((r == sr) ? self.y : 0.f);
    if (Ar != 0.f || Br != 0.f) {
#pragma unroll
      for (int j = 0; j < 32; j++)
        acc[j] += Ar * sU[r * 32 + j] + Br * sW[r * 32 + j];
    }
  }
#pragma unroll
  for (int j = 0; j < 32; j++) acc[j] = relu_(dv * acc[j] + sB2[j]);  // x2
  float x3[32];
#pragma unroll
  for (int j = 0; j < 32; j++) {
    float a = sBn[j];
#pragma unroll
    for (int q2 = 0; q2 < 32; q2++) a += acc[q2] * sWn[q2 * 32 + j];
    x3[j] = relu_(a);
  }
  float ps0 = 0.f, ps1 = 0.f, pd0 = 0.f, pd1 = 0.f;
#pragma unroll
  for (int j = 0; j < 32; j++) {
    float x = x3[j];
    ps0 += x * sM[(2 + j) * 2 + 0];
    ps1 += x * sM[(2 + j) * 2 + 1];
    pd0 += x * sM[(34 + j) * 2 + 0];
    pd1 += x * sM[(34 + j) * 2 + 1];
  }
  pspd[v] = make_float4(ps0, ps1, pd0, pd1);
}

#define UE 4
__global__ __launch_bounds__(256) void k_edge(const float* __restrict__ wsm,
                                              const int* __restrict__ src,
                                              const int* __restrict__ dst,
                                              const void* __restrict__ ewraw,
                                              const void* __restrict__ ceraw,
                                              const float4* __restrict__ pspd,
                                              void* __restrict__ out,
                                              const int* __restrict__ mode, int E) {
  int e0 = (blockIdx.x * blockDim.x + threadIdx.x) * UE;
  bool bf = (*mode) != 0;
  float b0 = wsm[O_BIAS2 + 0], b1 = wsm[O_BIAS2 + 1];
  float M00 = wsm[O_M + 0], M01 = wsm[O_M + 1];
  float M10 = wsm[O_M + 2], M11 = wsm[O_M + 3];
  if (e0 + UE <= E) {
    int s[UE], d[UE];
#pragma unroll
    for (int u = 0; u < UE; u++) { s[u] = src[e0 + u]; d[u] = dst[e0 + u]; }
    float4 s4[UE], d4[UE];
#pragma unroll
    for (int u = 0; u < UE; u++) s4[u] = pspd[s[u]];
#pragma unroll
    for (int u = 0; u < UE; u++) d4[u] = pspd[d[u]];
#pragma unroll
    for (int u = 0; u < UE; u++) {
      int e = e0 + u;
      float ew = bf ? bf2f(((const unsigned short*)ewraw)[e]) : ((const float*)ewraw)[e];
      float ce = bf ? bf2f(((const unsigned short*)ceraw)[e]) : ((const float*)ceraw)[e];
      float o0 = b0 + ew * M00 + ce * M10 + s4[u].x + d4[u].z;
      float o1 = b1 + ew * M01 + ce * M11 + s4[u].y + d4[u].w;
      if (bf) {
        unsigned int pk = ((unsigned int)f2bf(o1) << 16) | (unsigned int)f2bf(o0);
        ((unsigned int*)out)[e] = pk;
      } else {
        float2 r; r.x = o0; r.y = o1;
        ((float2*)out)[e] = r;
      }
    }
  } else {
    for (int e = e0; e < E; e++) {
      float ew = bf ? bf2f(((const unsigned short*)ewraw)[e]) : ((const float*)ewraw)[e];
      float ce = bf ? bf2f(((const unsigned short*)ceraw)[e]) : ((const float*)ceraw)[e];
      float4 s4 = pspd[src[e]];
      float4 d4 = pspd[dst[e]];
      float o0 = b0 + ew * M00 + ce * M10 + s4.x + d4.z;
      float o1 = b1 + ew * M01 + ce * M11 + s4.y + d4.w;
      if (bf) {
        unsigned int pk = ((unsigned int)f2bf(o1) << 16) | (unsigned int)f2bf(o0);
        ((unsigned int*)out)[e] = pk;
      } else {
        float2 r; r.x = o0; r.y = o1;
        ((float2*)out)[e] = r;
      }
    }
  }
}

extern "C" void kernel_launch(void* const* d_in, const int* in_sizes, int n_in,
                              void* d_out, int out_size, void* d_ws, size_t ws_size,
                              hipStream_t stream) {
  const int* eidx = (const int*)d_in[0];
  const int E = in_sizes[0] / 2;
  const int N = NNODES;
  const int* src = eidx;
  const int* dst = eidx + E;
  const int chunk = (E + FBC - 1) / FBC;

  char* ws = (char*)d_ws;
  size_t off = 0;
  size_t off_mode = off; off += 256;
  size_t off_wsm  = off; off += (size_t)WSM_TOTAL * 4;
  off = (off + 255) & ~(size_t)255;
  size_t off_cnts = off; off += (size_t)KB * FBC * 4;
  size_t off_tot  = off; off += (size_t)KB * 4;
  off = (off + 255) & ~(size_t)255;
  size_t off_base = off; off += (size_t)(KB + 1) * 4;
  off = (off + 255) & ~(size_t)255;
  size_t off_recs = off; off += (size_t)E * 4;
  size_t off_dinv = off; off += (size_t)N * 4;
  off = (off + 255) & ~(size_t)255;
  size_t off_rec4 = off; off += (size_t)N * 16;
  size_t off_pspd = off; off += (size_t)N * 16;
  off = (off + 255) & ~(size_t)255;
  size_t off_ABg  = off; off += (size_t)KB * ABSTR * 4;
  if (ws_size < off) return;

  int*          mode   = (int*)(ws + off_mode);
  float*        wsm    = (float*)(ws + off_wsm);
  int*          counts = (int*)(ws + off_cnts);
  int*          totals = (int*)(ws + off_tot);
  int*          bases  = (int*)(ws + off_base);
  unsigned int* recs   = (unsigned int*)(ws + off_recs);
  float*        dinv   = (float*)(ws + off_dinv);
  float4*       rec4   = (float4*)(ws + off_rec4);
  float4*       pspd   = (float4*)(ws + off_pspd);
  float*        ABg    = (float*)(ws + off_ABg);

  k_detect<<<1, 256, 0, stream>>>((const unsigned short*)d_in[1], mode);
  k_convert_small<<<(WSM_N + 255) / 256, 256, 0, stream>>>(
      d_in[4], d_in[5], d_in[6], d_in[7], d_in[8], d_in[9], d_in[10], d_in[11],
      d_in[12], d_in[13], d_in[14], d_in[15], mode, wsm);
  k_prep<<<1, 64, 0, stream>>>(wsm);
  k_hist<<<FBC, 1024, 0, stream>>>(dst, counts, E, chunk);
  k_scanA<<<KB, FBC, 0, stream>>>(counts, totals);
  k_scanB<<<1, 1024, 0, stream>>>(totals, bases);
  k_fillsort<<<FBC, 1024, 0, stream>>>(src, dst, counts, bases, recs, E, chunk);
  k_degdinv<<<KB, 1024, 0, stream>>>(recs, bases, dinv, N);
  k_sA<<<KB, 1024, 0, stream>>>(wsm, recs, bases, dinv, rec4, N);
  k_ABacc<<<KB, 1024, 0, stream>>>(recs, bases, rec4, ABg, N);
  k_node2<<<(N + 255) / 256, 256, 0, stream>>>(wsm, ABg, rec4, pspd, N);
  {
    long long tot = ((long long)E + UE - 1) / UE;
    int blocks = (int)((tot + 255) / 256);
    k_edge<<<blocks, 256, 0, stream>>>(wsm, src, dst, d_in[1], d_in[2],
                                       pspd, d_out, mode, E);
  }
}